// Round 13
// baseline (197.643 us; speedup 1.0000x reference)
//
#include <hip/hip_runtime.h>

// CRF NLL, round 22: bidirectional split, ONE chain wave per block, one wave
// per SIMD (the measured-fast residency).
//
// Measured: chain wave alone on its SIMD = 520 cy/step (R12c); two chain
// waves sharing = 840 (R17/R19); in-stream interleave of two chains = zero
// overlap (R20/R21: 1074 cy/pair). The per-step stall is a per-SIMD shared
// resource, so the fix is placement, not scheduling: 1024 x 64-thread
// blocks with waves_per_eu(1,1) -> 1024 waves on 1024 SIMDs, every chain
// wave alone. Fwd/bwd halves of batch b (blocks b and b+512) meet via
// d_ws: publish state + ksum, __threadfence, atomicAdd flag; second
// arriver combines. Gold score split (s<256 on fwd, s>=256 on bwd).
// Chain body/numerics identical to R19 (verified absmax 0.0).
#define BB 512
#define SS 512
#define TT 64
#define START_TAG 62
#define STOP_TAG 63

#define LOG2E 1.4426950408889634f
#define LN2   0.6931471805599453f

typedef _Float16 h2 __attribute__((ext_vector_type(2)));
typedef _Float16 h8 __attribute__((ext_vector_type(8)));
typedef float    f4 __attribute__((ext_vector_type(4)));

__device__ __forceinline__ h2 pkrtz(float a, float b) {
    return __builtin_bit_cast(h2, __builtin_amdgcn_cvt_pkrtz(a, b));
}
__device__ __forceinline__ f4 MF(h8 a, h8 b, f4 c) {
    return __builtin_amdgcn_mfma_f32_16x16x32_f16(a, b, c, 0, 0, 0);
}

// workspace layout (byte offsets from d_ws)
#define WS_FLAG(ws)  ((int*)(ws))                              // [512]
#define WS_V(ws)     ((float*)((char*)(ws) + 2048))            // [512][64]
#define WS_U(ws)     ((float*)((char*)(ws) + 2048 + 131072))   // [512][64]
#define WS_K(ws)     ((int*)((char*)(ws) + 2048 + 262144))     // [512][2]

__global__ void __launch_bounds__(64)
__attribute__((amdgpu_waves_per_eu(1, 1))) crf_main(
    const float* __restrict__ feats, const int* __restrict__ mask,
    const int* __restrict__ tags, const float* __restrict__ trans,
    float* __restrict__ out, void* __restrict__ ws)
{
    const int bid  = blockIdx.x;
    const bool isF = (bid < BB);
    const int b    = isF ? bid : (bid - BB);
    const int lane = threadIdx.x & 63;
    const int g    = lane >> 4;
    const int cg   = lane & 15;

    const float* frow = feats + (size_t)b * SS * TT;
    const int*   mrow = mask + b * SS;

    __shared__ __align__(16) _Float16 febw[8][TT];

    int cnt = 0;
    #pragma unroll
    for (int s = lane; s < SS; s += 64) cnt += (mrow[s] != 0);
    #pragma unroll
    for (int off = 32; off; off >>= 1) cnt += __shfl_xor(cnt, off);
    const int len = cnt;            // in [SS/2, SS]
    const int h   = len >> 1;

    // ---------------- gold-score half (split across the block pair) -------
    {
        const int* trow = tags + b * SS;
        float acc = 0.f;
        const int s0 = isF ? lane : (256 + lane);
        const int s1 = isF ? 256 : 512;
        for (int s = s0; s < s1; s += 64) {
            if (mrow[s] != 0) {
                const int tag  = trow[s];
                const int prev = (s == 0) ? START_TAG : trow[s - 1];
                acc += frow[(size_t)s * TT + tag] + trans[prev * TT + tag];
            }
        }
        #pragma unroll
        for (int off = 32; off; off >>= 1) acc += __shfl_xor(acc, off);
        if (lane == 0) {
            float extra = 0.f;
            if (!isF) extra = trans[trow[len - 1] * TT + STOP_TAG];
            atomicAdd(out, -(acc + extra));
        }
    }

    // ---------------- chain parameters ----------------
    const int to_base = 16 * (cg >> 2) + (cg & 3);
    const int nstep = isF ? h : (len - h - 2);
    const int base  = isF ? 1 : (len - 2);
    const int dir   = isF ? 1 : -1;

    // A fragments: fwd = exp(trans[kt][ot]) (M^T), bwd = exp(trans[ot][kt])
    h8 A[4][2];
    #pragma unroll
    for (int tt = 0; tt < 4; ++tt)
        #pragma unroll
        for (int kc = 0; kc < 2; ++kc)
            #pragma unroll
            for (int j = 0; j < 8; ++j) {
                const int kt = 16 * g + 8 * kc + j;
                const int ot = to_base + 4 * tt;
                const int ix = isF ? (kt * TT + ot) : (ot * TT + kt);
                A[tt][kc][j] =
                    (_Float16)__builtin_amdgcn_exp2f(trans[ix] * LOG2E);
            }

    // B init (slots = raw tags 16g+sl)
    h8 B0, B1;
    if (isF) {
        const float offs = frow[0] + trans[START_TAG * TT + 0];
        #pragma unroll
        for (int sl = 0; sl < 8; ++sl) {
            const int t0 = 16 * g + sl, t1 = t0 + 8;
            B0[sl] = (_Float16)__builtin_amdgcn_exp2f(
                (frow[t0] + trans[START_TAG * TT + t0] - offs) * LOG2E);
            B1[sl] = (_Float16)__builtin_amdgcn_exp2f(
                (frow[t1] + trans[START_TAG * TT + t1] - offs) * LOG2E);
        }
    } else {
        const float* fl = frow + (size_t)(len - 1) * TT;
        #pragma unroll
        for (int sl = 0; sl < 8; ++sl) {
            const int t0 = 16 * g + sl, t1 = t0 + 8;
            B0[sl] = (_Float16)__builtin_amdgcn_exp2f(
                (fl[t0] + trans[t0 * TT + STOP_TAG]) * LOG2E);
            B1[sl] = (_Float16)__builtin_amdgcn_exp2f(
                (fl[t1] + trans[t1 * TT + STOP_TAG]) * LOG2E);
        }
    }
    int ksum = 0;

    auto rowOf = [&](int idx) {
        int r = base + dir * idx;
        return r < 0 ? 0 : (r > SS - 1 ? SS - 1 : r);
    };

    // raw-feat ring (rows for steps i..i+7)
    float fr[8];
    #pragma unroll
    for (int j = 0; j < 8; ++j)
        fr[j] = frow[(size_t)rowOf(j) * TT + lane];
    // prologue: fe rows for steps 0..3
    #pragma unroll
    for (int j = 0; j < 4; ++j)
        febw[rowOf(j) & 7][lane] =
            (_Float16)__builtin_amdgcn_exp2f(fr[j] * LOG2E);

    const f4 Zz = {0.f, 0.f, 0.f, 0.f};
    auto STEP = [&](int row) {
        const _Float16* fb = &febw[row & 7][16 * g];
        const h8 feL = *(const h8*)(fb);
        const h8 feH = *(const h8*)(fb + 8);
        f4 d0 = MF(A[0][0], B0, Zz);
        f4 d1 = MF(A[1][0], B0, Zz);
        f4 d2 = MF(A[2][0], B0, Zz);
        f4 d3 = MF(A[3][0], B0, Zz);
        d0 = MF(A[0][1], B1, d0);
        d1 = MF(A[1][1], B1, d1);
        d2 = MF(A[2][1], B1, d2);
        d3 = MF(A[3][1], B1, d3);
        const int eb = (__builtin_amdgcn_readfirstlane(
                            __float_as_int(d0[0])) >> 23) & 0xff;
        ksum += eb - 127;
        const float sc = __int_as_float((254 - eb) << 23);
        const h2 p0 = pkrtz(d0[0] * sc, d0[1] * sc);
        const h2 p1 = pkrtz(d0[2] * sc, d0[3] * sc);
        const h2 p2 = pkrtz(d1[0] * sc, d1[1] * sc);
        const h2 p3 = pkrtz(d1[2] * sc, d1[3] * sc);
        const h2 p4 = pkrtz(d2[0] * sc, d2[1] * sc);
        const h2 p5 = pkrtz(d2[2] * sc, d2[3] * sc);
        const h2 p6 = pkrtz(d3[0] * sc, d3[1] * sc);
        const h2 p7 = pkrtz(d3[2] * sc, d3[3] * sc);
        const h2 q0 = p0 * __builtin_shufflevector(feL, feL, 0, 1);
        const h2 q1 = p1 * __builtin_shufflevector(feL, feL, 2, 3);
        const h2 q2 = p2 * __builtin_shufflevector(feL, feL, 4, 5);
        const h2 q3 = p3 * __builtin_shufflevector(feL, feL, 6, 7);
        const h2 q4 = p4 * __builtin_shufflevector(feH, feH, 0, 1);
        const h2 q5 = p5 * __builtin_shufflevector(feH, feH, 2, 3);
        const h2 q6 = p6 * __builtin_shufflevector(feH, feH, 4, 5);
        const h2 q7 = p7 * __builtin_shufflevector(feH, feH, 6, 7);
        B0 = __builtin_shufflevector(
                 __builtin_shufflevector(q0, q1, 0, 1, 2, 3),
                 __builtin_shufflevector(q2, q3, 0, 1, 2, 3),
                 0, 1, 2, 3, 4, 5, 6, 7);
        B1 = __builtin_shufflevector(
                 __builtin_shufflevector(q4, q5, 0, 1, 2, 3),
                 __builtin_shufflevector(q6, q7, 0, 1, 2, 3),
                 0, 1, 2, 3, 4, 5, 6, 7);
    };

    int i = 0;
    for (; i + 3 < nstep; i += 4) {
        const float n0 = frow[(size_t)rowOf(i + 8)  * TT + lane];
        const float n1 = frow[(size_t)rowOf(i + 9)  * TT + lane];
        const float n2 = frow[(size_t)rowOf(i + 10) * TT + lane];
        const float n3 = frow[(size_t)rowOf(i + 11) * TT + lane];
        febw[rowOf(i + 4) & 7][lane] =
            (_Float16)__builtin_amdgcn_exp2f(fr[4] * LOG2E);
        febw[rowOf(i + 5) & 7][lane] =
            (_Float16)__builtin_amdgcn_exp2f(fr[5] * LOG2E);
        febw[rowOf(i + 6) & 7][lane] =
            (_Float16)__builtin_amdgcn_exp2f(fr[6] * LOG2E);
        febw[rowOf(i + 7) & 7][lane] =
            (_Float16)__builtin_amdgcn_exp2f(fr[7] * LOG2E);

        STEP(rowOf(i)); STEP(rowOf(i + 1));
        STEP(rowOf(i + 2)); STEP(rowOf(i + 3));

        #pragma unroll
        for (int j = 0; j < 4; ++j) fr[j] = fr[j + 4];
        fr[4] = n0; fr[5] = n1; fr[6] = n2; fr[7] = n3;
    }

    const int rem = nstep - i;   // 0..3
    if (rem > 0) STEP(rowOf(i));
    if (rem > 1) STEP(rowOf(i + 1));
    if (rem > 2) STEP(rowOf(i + 2));

    // ---------------- publish half-chain state to workspace ----------------
    float* Vws = WS_V(ws) + b * TT;
    float* Uws = WS_U(ws) + b * TT;
    int*   Kws = WS_K(ws) + b * 2;

    if (isF) {
        // V = M^T E_h (bare matvec, rescaled)
        f4 d0 = MF(A[0][0], B0, Zz);
        f4 d1 = MF(A[1][0], B0, Zz);
        f4 d2 = MF(A[2][0], B0, Zz);
        f4 d3 = MF(A[3][0], B0, Zz);
        d0 = MF(A[0][1], B1, d0);
        d1 = MF(A[1][1], B1, d1);
        d2 = MF(A[2][1], B1, d2);
        d3 = MF(A[3][1], B1, d3);
        const int eb = (__builtin_amdgcn_readfirstlane(
                            __float_as_int(d0[0])) >> 23) & 0xff;
        ksum += eb - 127;
        const float sc = __int_as_float((254 - eb) << 23);
        if (cg == 0) {
            #pragma unroll
            for (int r = 0; r < 4; ++r) {
                Vws[16 * g + 0 * 4 + r] = d0[r] * sc;
                Vws[16 * g + 1 * 4 + r] = d1[r] * sc;
                Vws[16 * g + 2 * 4 + r] = d2[r] * sc;
                Vws[16 * g + 3 * 4 + r] = d3[r] * sc;
            }
        }
        if (lane == 0) Kws[0] = ksum;
    } else {
        if (cg == 0) {
            #pragma unroll
            for (int sl = 0; sl < 8; ++sl) {
                Uws[16 * g + sl]     = (float)B0[sl];
                Uws[16 * g + 8 + sl] = (float)B1[sl];
            }
        }
        if (lane == 0) Kws[1] = ksum;
    }

    // ---------------- rendezvous: second arriver combines ----------------
    __threadfence();
    int old = 0;
    if (lane == 0) old = atomicAdd(&WS_FLAG(ws)[b], 1);
    old = __shfl(old, 0);
    if (old == 1) {
        __threadfence();
        const volatile float* Vv = Vws;
        const volatile float* Uv = Uws;
        const volatile int*   Kv = Kws;
        float z = Vv[lane] * Uv[lane];
        #pragma unroll
        for (int off = 32; off; off >>= 1) z += __shfl_xor(z, off);
        if (lane == 0) {
            const float offs = frow[0] + trans[START_TAG * TT + 0];
            atomicAdd(out, offs + (float)(Kv[0] + Kv[1]) * LN2
                           + LN2 * __builtin_amdgcn_logf(z));
        }
    }
}

extern "C" void kernel_launch(void* const* d_in, const int* in_sizes, int n_in,
                              void* d_out, int out_size, void* d_ws, size_t ws_size,
                              hipStream_t stream) {
    const float* feats = (const float*)d_in[0];   // (B,S,T) f32
    const int*   mask  = (const int*)d_in[1];     // (B,S)   int (0/1)
    const int*   tags  = (const int*)d_in[2];     // (B,S)   int
    const float* trans = (const float*)d_in[3];   // (T,T)   f32
    float* out = (float*)d_out;

    (void)hipMemsetAsync(out, 0, sizeof(float), stream);
    (void)hipMemsetAsync(d_ws, 0, 2048, stream);   // per-batch flags
    crf_main<<<2 * BB, 64, 0, stream>>>(feats, mask, tags, trans, out, d_ws);
}